// Round 1
// baseline (452.297 us; speedup 1.0000x reference)
//
#include <hip/hip_runtime.h>

typedef __attribute__((ext_vector_type(8))) short short8;
typedef __attribute__((ext_vector_type(4))) float f32x4;

#define C_DIM 2048
#define KW 256
#define HW_DIM 4096

__device__ __forceinline__ short f2bf(float f) {
    unsigned u = __builtin_bit_cast(unsigned, f);
    unsigned r = (u + 0x7fffu + ((u >> 16) & 1u)) >> 16;
    return (short)r;
}

// ---------- Kernel 1: normalize centroid -> bf16 w_norm; zero x_hist/counts ----------
__global__ __launch_bounds__(256) void k1_prep(const float* __restrict__ centroid,
                                               short* __restrict__ wnorm,
                                               float* __restrict__ xhist,
                                               int* __restrict__ counts) {
    const int row = blockIdx.x, t = threadIdx.x;
    const float* src = centroid + row * C_DIM;
    float v[8]; float ss = 0.f;
#pragma unroll
    for (int i = 0; i < 8; ++i) { v[i] = src[t + 256 * i]; ss += v[i] * v[i]; }
#pragma unroll
    for (int off = 1; off < 64; off <<= 1) ss += __shfl_xor(ss, off);
    __shared__ float red[4];
    if ((t & 63) == 0) red[t >> 6] = ss;
    __syncthreads();
    const float tot = red[0] + red[1] + red[2] + red[3];
    const float inv = 1.0f / fmaxf(sqrtf(tot), 1e-12f);
#pragma unroll
    for (int i = 0; i < 8; ++i) wnorm[row * C_DIM + t + 256 * i] = f2bf(v[i] * inv);
    if (row == 0) {
        for (int i = t; i < 2048; i += 256) { xhist[i] = 0.f; counts[i] = 0; }
    }
}

// ---------- Kernel 2: fused GEMM (bf16 MFMA) + norm + softmax + argmax + hist ----------
// Block: 256 thr (4 waves). Tile: M=256 k-words x N=64 pixels, K-chunk=64 channels.
// Wave w owns k-words [64w, 64w+64). grid = 32768/64 = 512 blocks.
__global__ __launch_bounds__(256, 2) void k2_main(const float* __restrict__ x,
                                                  const short* __restrict__ wnorm,
                                                  float* __restrict__ xcorr,
                                                  float* __restrict__ xhist,
                                                  int* __restrict__ labels,
                                                  int* __restrict__ counts) {
    __shared__ float sf[64 * 68];        // f32 staging tile [c:64][n stride 68]
    __shared__ short bfr[8 * 64 * 8];    // bf16 frag tile [unit:8][n:64][8c]
    __shared__ float ssred[4][64];
    __shared__ float invn[64];
    __shared__ float wmax[4][64];
    __shared__ int   warg[4][64];
    __shared__ float wred[4][64];
    __shared__ float Mn[64];
    __shared__ float Sn[64];

    const int t = threadIdx.x;
    const int w = t >> 6, l = t & 63;
    const int p = l & 15, g = l >> 4;
    const int n0 = blockIdx.x * 64;
    const int b = n0 >> 12, hw0 = n0 & 4095;
    const float* xb = x + (size_t)b * C_DIM * HW_DIM + hw0;
    const short* wrow = wnorm + (w * 64 + p) * C_DIM;

    f32x4 acc[4][4];
#pragma unroll
    for (int i = 0; i < 4; ++i)
#pragma unroll
        for (int j = 0; j < 4; ++j) acc[i][j] = (f32x4)0.f;

    float ss = 0.f;

#pragma unroll 1
    for (int cc = 0; cc < 32; ++cc) {
        const int cb = cc * 64;
        // stage f32 [64c][64n] tile, coalesced float4
#pragma unroll
        for (int q = 0; q < 4; ++q) {
            const int lin = t + q * 256;
            const int row = lin >> 4, c4 = (lin & 15) << 2;
            *(float4*)(&sf[row * 68 + c4]) =
                *(const float4*)(xb + (size_t)(cb + row) * HW_DIM + c4);
        }
        __syncthreads();
        // transpose: lane -> pixel n=l, c in [16w,16w+16); accumulate sumsq (exact f32)
        float tv[16];
#pragma unroll
        for (int j = 0; j < 16; ++j) {
            tv[j] = sf[(16 * w + j) * 68 + l];
            ss += tv[j] * tv[j];
        }
        short8 pk0, pk1;
#pragma unroll
        for (int j = 0; j < 8; ++j) { pk0[j] = f2bf(tv[j]); pk1[j] = f2bf(tv[8 + j]); }
        *(short8*)(&bfr[((2 * w + 0) * 64 + l) * 8]) = pk0;
        *(short8*)(&bfr[((2 * w + 1) * 64 + l) * 8]) = pk1;
        __syncthreads();
        // MFMA: A = w_norm rows (global, per-lane 16B), B = bfr frags
#pragma unroll
        for (int ks = 0; ks < 2; ++ks) {
            short8 af[4], bf[4];
#pragma unroll
            for (int mf = 0; mf < 4; ++mf)
                af[mf] = *(const short8*)(wrow + mf * 16 * C_DIM + cb + ks * 32 + g * 8);
#pragma unroll
            for (int nf = 0; nf < 4; ++nf)
                bf[nf] = *(const short8*)(&bfr[((ks * 4 + g) * 64 + nf * 16 + p) * 8]);
#pragma unroll
            for (int mf = 0; mf < 4; ++mf)
#pragma unroll
                for (int nf = 0; nf < 4; ++nf)
                    acc[mf][nf] = __builtin_amdgcn_mfma_f32_16x16x32_bf16(
                        af[mf], bf[nf], acc[mf][nf], 0, 0, 0);
        }
        __syncthreads();
    }

    // ---- epilogue: pixel norms ----
    ssred[w][l] = ss;
    __syncthreads();
    if (t < 64) {
        const float s = ssred[0][t] + ssred[1][t] + ssred[2][t] + ssred[3][t];
        invn[t] = 1.0f / fmaxf(sqrtf(s), 1e-12f);
    }
    __syncthreads();
    float inv[4];
#pragma unroll
    for (int nf = 0; nf < 4; ++nf) inv[nf] = invn[nf * 16 + p];

    // ---- max / argmax over k (lane-local 16, then lanes xor16/32, then waves) ----
    float mx[4]; int ai[4];
#pragma unroll
    for (int nf = 0; nf < 4; ++nf) { mx[nf] = -3.0e38f; ai[nf] = 0; }
#pragma unroll
    for (int mf = 0; mf < 4; ++mf)
#pragma unroll
        for (int r = 0; r < 4; ++r) {
            const int k = w * 64 + mf * 16 + g * 4 + r;
#pragma unroll
            for (int nf = 0; nf < 4; ++nf) {
                const float v = acc[mf][nf][r] * inv[nf];
                if (v > mx[nf]) { mx[nf] = v; ai[nf] = k; }
            }
        }
#pragma unroll
    for (int off = 16; off <= 32; off <<= 1)
#pragma unroll
        for (int nf = 0; nf < 4; ++nf) {
            const float ov = __shfl_xor(mx[nf], off);
            const int   oi = __shfl_xor(ai[nf], off);
            if (ov > mx[nf] || (ov == mx[nf] && oi < ai[nf])) { mx[nf] = ov; ai[nf] = oi; }
        }
    if (l < 16) {
#pragma unroll
        for (int nf = 0; nf < 4; ++nf) { wmax[w][nf * 16 + l] = mx[nf]; warg[w][nf * 16 + l] = ai[nf]; }
    }
    __syncthreads();
    if (t < 64) {
        float m = wmax[0][t]; int a = warg[0][t];
#pragma unroll
        for (int ww = 1; ww < 4; ++ww) {
            const float om = wmax[ww][t]; const int oa = warg[ww][t];
            if (om > m || (om == m && oa < a)) { m = om; a = oa; }
        }
        Mn[t] = m;
        labels[n0 + t] = a;
        atomicAdd(&counts[b * KW + a], 1);
    }
    __syncthreads();
    float mn[4];
#pragma unroll
    for (int nf = 0; nf < 4; ++nf) mn[nf] = Mn[nf * 16 + p];

    // ---- sum of exp ----
    float se[4] = {0.f, 0.f, 0.f, 0.f};
#pragma unroll
    for (int mf = 0; mf < 4; ++mf)
#pragma unroll
        for (int r = 0; r < 4; ++r)
#pragma unroll
            for (int nf = 0; nf < 4; ++nf)
                se[nf] += __expf(acc[mf][nf][r] * inv[nf] - mn[nf]);
#pragma unroll
    for (int off = 16; off <= 32; off <<= 1)
#pragma unroll
        for (int nf = 0; nf < 4; ++nf) se[nf] += __shfl_xor(se[nf], off);
    if (l < 16) {
#pragma unroll
        for (int nf = 0; nf < 4; ++nf) wred[w][nf * 16 + l] = se[nf];
    }
    __syncthreads();
    if (t < 64) Sn[t] = wred[0][t] + wred[1][t] + wred[2][t] + wred[3][t];
    __syncthreads();

    float rs[4];
#pragma unroll
    for (int nf = 0; nf < 4; ++nf) rs[nf] = 1.0f / Sn[nf * 16 + p];

    // ---- write softmax (x_corr is k-major: matches D[k][n]) + x_hist partials ----
    float hist[4][4];
#pragma unroll
    for (int mf = 0; mf < 4; ++mf)
#pragma unroll
        for (int r = 0; r < 4; ++r) hist[mf][r] = 0.f;
#pragma unroll
    for (int mf = 0; mf < 4; ++mf)
#pragma unroll
        for (int r = 0; r < 4; ++r) {
            const int k = w * 64 + mf * 16 + g * 4 + r;
            float* orow = xcorr + ((size_t)(b * KW + k) << 12) + hw0;
#pragma unroll
            for (int nf = 0; nf < 4; ++nf) {
                const float pr = __expf(acc[mf][nf][r] * inv[nf] - mn[nf]) * rs[nf];
                orow[nf * 16 + p] = pr;
                hist[mf][r] += pr;
            }
        }
#pragma unroll
    for (int off = 1; off <= 8; off <<= 1)
#pragma unroll
        for (int mf = 0; mf < 4; ++mf)
#pragma unroll
            for (int r = 0; r < 4; ++r) hist[mf][r] += __shfl_xor(hist[mf][r], off);
    if (p == 0) {
#pragma unroll
        for (int mf = 0; mf < 4; ++mf)
#pragma unroll
            for (int r = 0; r < 4; ++r)
                unsafeAtomicAdd(&xhist[b * KW + w * 64 + mf * 16 + g * 4 + r], hist[mf][r]);
    }
}

// ---------- Kernel 3: label scatter -> per-(batch, c-slice) LDS histogram ----------
// grid 256 = 32 c-chunks x 8 batches. LDS [256k][64c] XOR-swizzled.
__global__ __launch_bounds__(256) void k3_scatter(const float* __restrict__ x,
                                                  const int* __restrict__ labels,
                                                  float* __restrict__ partial) {
    __shared__ float part[KW * 64];   // 64 KiB
    const int t = threadIdx.x;
    const int ci = blockIdx.x & 31, b = blockIdx.x >> 5;
    for (int i = t; i < KW * 64; i += 256) part[i] = 0.f;
    __syncthreads();
    const int cb = ci * 64;
    const float* xb = x + (size_t)(b * C_DIM + cb) * HW_DIM;
    const int* lb = labels + b * HW_DIM;
#pragma unroll 1
    for (int pg = 0; pg < 4; ++pg) {
        const int pl = pg * 1024 + t * 4;
        const int4 lv = *(const int4*)(lb + pl);
        const int a0 = lv.x << 6, a1 = lv.y << 6, a2 = lv.z << 6, a3 = lv.w << 6;
        const int s0 = lv.x & 63, s1 = lv.y & 63, s2 = lv.z & 63, s3 = lv.w & 63;
        for (int c = 0; c < 64; ++c) {
            const float4 v = *(const float4*)(xb + (size_t)c * HW_DIM + pl);
            unsafeAtomicAdd(&part[a0 + (c ^ s0)], v.x);
            unsafeAtomicAdd(&part[a1 + (c ^ s1)], v.y);
            unsafeAtomicAdd(&part[a2 + (c ^ s2)], v.z);
            unsafeAtomicAdd(&part[a3 + (c ^ s3)], v.w);
        }
    }
    __syncthreads();
    for (int i = t; i < KW * 64; i += 256) {
        const int k = i >> 6, c = i & 63;
        partial[((size_t)(b * KW + k) << 11) + cb + c] = part[(k << 6) + (c ^ (k & 63))];
    }
}

// ---------- Kernel 4: reduce partials, EMA update, y_word ----------
__global__ __launch_bounds__(256) void k4_final(const float* __restrict__ partial,
                                                const int* __restrict__ counts,
                                                const float* __restrict__ centroid,
                                                float* __restrict__ out_c,
                                                float* __restrict__ y_word) {
    const int idx = blockIdx.x * 256 + threadIdx.x;   // 0..524287
    const int k = idx >> 11, c = idx & 2047;
    float s = 0.f;
#pragma unroll
    for (int pi = 0; pi < 8; ++pi) s += partial[((size_t)(pi * KW + k) << 11) + c];
    int cnt = 0;
#pragma unroll
    for (int bb = 0; bb < 8; ++bb) cnt += counts[bb * KW + k];
    const float ctr = s / ((float)cnt + 1e-4f);
    out_c[idx] = 0.01f * ctr + 0.99f * centroid[idx];
    if (idx < 2048) y_word[idx] = (counts[idx] > 0) ? 1.0f : 0.0f;
}

extern "C" void kernel_launch(void* const* d_in, const int* in_sizes, int n_in,
                              void* d_out, int out_size, void* d_ws, size_t ws_size,
                              hipStream_t stream) {
    const float* x        = (const float*)d_in[0];
    const float* centroid = (const float*)d_in[1];
    float* out   = (float*)d_out;
    float* xcorr = out;                 // 8*256*4096
    float* xhist = out + 8388608;       // 2048
    float* yword = out + 8390656;       // 2048
    float* outc  = out + 8392704;       // 256*2048

    char* ws = (char*)d_ws;
    short* wnorm   = (short*)ws;                                    // 1 MiB
    int*   labels  = (int*)(ws + (1 << 20));                        // 128 KiB
    int*   counts  = (int*)(ws + (1 << 20) + 131072);               // 8 KiB
    float* partial = (float*)(ws + (1 << 20) + 131072 + 8192);      // 16 MiB

    hipLaunchKernelGGL(k1_prep,    dim3(256),  dim3(256), 0, stream, centroid, wnorm, xhist, counts);
    hipLaunchKernelGGL(k2_main,    dim3(512),  dim3(256), 0, stream, x, wnorm, xcorr, xhist, labels, counts);
    hipLaunchKernelGGL(k3_scatter, dim3(256),  dim3(256), 0, stream, x, labels, partial);
    hipLaunchKernelGGL(k4_final,   dim3(2048), dim3(256), 0, stream, partial, counts, centroid, outc, yword);
}